// Round 10
// baseline (109.932 us; speedup 1.0000x reference)
//
#include <hip/hip_runtime.h>

typedef float f32x2 __attribute__((ext_vector_type(2)));
typedef float f32x4 __attribute__((ext_vector_type(4)));
typedef __bf16 bf16x8 __attribute__((ext_vector_type(8)));
typedef unsigned short u16x2 __attribute__((ext_vector_type(2)));
typedef unsigned short u16x4 __attribute__((ext_vector_type(4)));
typedef unsigned short u16x8 __attribute__((ext_vector_type(8)));

#define BSH 4            // bucket = 16 dst nodes
#define BN 16
#define CAPFIX 512       // slots per bucket region (mean 256, +16 sigma)
#define PNB_MAX 3200     // >= nbuck = ceil(50000/16) = 3125
#define PCH 16384        // edges per partition block (49 blocks)
#define PEPT (PCH / 256) // 64 edges per thread
#define FC_ROWS 64

__device__ inline unsigned short f2bf(float x) {
  unsigned int u = __builtin_bit_cast(unsigned int, x);
  unsigned int r = (u + 0x7FFFu + ((u >> 16) & 1u)) >> 16;
  return (unsigned short)r;
}
__device__ inline float bf2f(unsigned short h) {
  unsigned int u = ((unsigned int)h) << 16;
  return __builtin_bit_cast(float, u);
}

// ---------------- prezero: zero bcursor (blocks >= 8) + pack W (blocks 0..7) ----------------
__global__ __launch_bounds__(256) void prezero_kernel(const float* __restrict__ W,
                                                      unsigned short* __restrict__ wtp,
                                                      int* __restrict__ bcursor, int n) {
  int b = blockIdx.x;
  if (b < 8) {
    int tid = b * 256 + threadIdx.x;  // 2048 chunks
    int col = tid & 127;
    int kg = tid >> 7;
    float v[8];
#pragma unroll
    for (int j = 0; j < 8; ++j) v[j] = W[(kg * 8 + j) * 128 + col];
    u16x8 pk = {f2bf(v[0]), f2bf(v[1]), f2bf(v[2]), f2bf(v[3]),
                f2bf(v[4]), f2bf(v[5]), f2bf(v[6]), f2bf(v[7])};
    *(u16x8*)&wtp[(size_t)(kg * 128 + col) * 8] = pk;
  } else {
    int i = (b - 8) * 256 + threadIdx.x;
    if (i < n) bcursor[i] = 0;
  }
}

// ---------------- partition body: two-pass (count; reserve; re-read + scatter) ----------------
__device__ void partition_body(char* smem, const int* __restrict__ src,
                               const int* __restrict__ dst,
                               int* __restrict__ bcursor, int* __restrict__ tmp,
                               int E, int nbuck, int blk) {
  int* cnt = (int*)smem;
  int* lcur = cnt + PNB_MAX;
  int t = threadIdx.x;
  int base = blk * PCH;
  for (int i = t; i < nbuck; i += 256) cnt[i] = 0;
  __syncthreads();
  // pass 1: LDS histogram
  for (int i = 0; i < PEPT; ++i) {
    int e = base + t + i * 256;
    if (e < E) atomicAdd(&cnt[dst[e] >> BSH], 1);
  }
  __syncthreads();
  // reserve contiguous ranges in each bucket region
  for (int i = t; i < nbuck; i += 256) {
    int c = cnt[i];
    lcur[i] = c ? atomicAdd(&bcursor[i], c) : 0;
  }
  __syncthreads();
  // pass 2: re-read edges (L2-hot), scatter records
  for (int i = 0; i < PEPT; ++i) {
    int e = base + t + i * 256;
    if (e < E) {
      int d = dst[e];
      int b = d >> BSH;
      int rec = (src[e] & 0xFFFF) | ((d & (BN - 1)) << 16);
      int p = atomicAdd(&lcur[b], 1);
      if (p < CAPFIX) tmp[(size_t)b * CAPFIX + p] = rec;
    }
  }
}

// ---------------- fc body: h = feat @ W via MFMA; B-fragments from L1-resident wtp ----------------
__device__ void fc_body(char* smem, const float* __restrict__ feat,
                        const unsigned short* __restrict__ wtp,
                        const float* __restrict__ al, const float* __restrict__ ar,
                        unsigned short* __restrict__ hbf,
                        float* __restrict__ el, float* __restrict__ er,
                        int N, int blk) {
  unsigned short* Albs = (unsigned short*)smem;  // 16 KB
  int t = threadIdx.x;
  int row0 = blk * FC_ROWS;
#pragma unroll
  for (int i = 0; i < 4; ++i) {
    int ch = i * 256 + t;
    int row = ch >> 4;
    int kg = ch & 15;
    int grow = row0 + row;
    f32x4 x0 = {}, x1 = {};
    if (grow < N) {
      const f32x4* fp = (const f32x4*)(feat + (size_t)grow * 128 + kg * 8);
      x0 = fp[0];
      x1 = fp[1];
    }
    int sc = kg * 64 + (row ^ kg);
    u16x8 pk = {f2bf(x0[0]), f2bf(x0[1]), f2bf(x0[2]), f2bf(x0[3]),
                f2bf(x1[0]), f2bf(x1[1]), f2bf(x1[2]), f2bf(x1[3])};
    *(u16x8*)&Albs[sc * 8] = pk;
  }
  __syncthreads();
  int w = t >> 6;
  int l = t & 63;
  int lr = l & 15;
  int lhi = l >> 4;
  f32x4 acc[8] = {};
  bf16x8 afr[4];
#pragma unroll
  for (int ks = 0; ks < 4; ++ks) {
    int kg = ks * 4 + lhi;
    int row = w * 16 + lr;
    afr[ks] = *(const bf16x8*)&Albs[(kg * 64 + (row ^ kg)) * 8];
  }
#pragma unroll
  for (int nt = 0; nt < 8; ++nt) {
#pragma unroll
    for (int ks = 0; ks < 4; ++ks) {
      int kg = ks * 4 + lhi;
      int col = nt * 16 + lr;
      bf16x8 b = *(const bf16x8*)&wtp[(size_t)(kg * 128 + col) * 8];
      acc[nt] = __builtin_amdgcn_mfma_f32_16x16x32_bf16(afr[ks], b, acc[nt], 0, 0, 0);
    }
  }
#pragma unroll
  for (int nt = 0; nt < 8; ++nt) {
#pragma unroll
    for (int r = 0; r < 4; ++r) {
      int g = row0 + w * 16 + lhi * 4 + r;
      if (g < N) hbf[(size_t)g * 128 + nt * 16 + lr] = f2bf(acc[nt][r]);
    }
  }
  f32x4 pl[4] = {}, pr[4] = {};
#pragma unroll
  for (int nt = 0; nt < 8; ++nt) {
    int hd = nt >> 1;
    float wl = al[nt * 16 + lr];
    float wr = ar[nt * 16 + lr];
#pragma unroll
    for (int r = 0; r < 4; ++r) {
      pl[r][hd] += acc[nt][r] * wl;
      pr[r][hd] += acc[nt][r] * wr;
    }
  }
#pragma unroll
  for (int off = 1; off < 16; off <<= 1) {
#pragma unroll
    for (int r = 0; r < 4; ++r) {
#pragma unroll
      for (int c = 0; c < 4; ++c) {
        pl[r][c] += __shfl_xor(pl[r][c], off);
        pr[r][c] += __shfl_xor(pr[r][c], off);
      }
    }
  }
  if (lr == 0) {
#pragma unroll
    for (int r = 0; r < 4; ++r) {
      int g = row0 + w * 16 + lhi * 4 + r;
      if (g < N) *(f32x4*)(el + (size_t)g * 4) = pl[r];
    }
  } else if (lr == 1) {
#pragma unroll
    for (int r = 0; r < 4; ++r) {
      int g = row0 + w * 16 + lhi * 4 + r;
      if (g < N) *(f32x4*)(er + (size_t)g * 4) = pr[r];
    }
  }
}

// ---------------- fused: partition blocks + fc blocks in one grid ----------------
__global__ __launch_bounds__(256) void fused_pfc(const int* __restrict__ src,
                                                 const int* __restrict__ dst,
                                                 int* __restrict__ bcursor,
                                                 int* __restrict__ tmp,
                                                 const float* __restrict__ feat,
                                                 const unsigned short* __restrict__ wtp,
                                                 const float* __restrict__ al,
                                                 const float* __restrict__ ar,
                                                 unsigned short* __restrict__ hbf,
                                                 float* __restrict__ el,
                                                 float* __restrict__ er,
                                                 int E, int N, int nbuck, int npart) {
  __shared__ alignas(16) char smem[PNB_MAX * 8];  // 25.6 KB union (partition 25.6, fc 16)
  if ((int)blockIdx.x < npart)
    partition_body(smem, src, dst, bcursor, tmp, E, nbuck, blockIdx.x);
  else
    fc_body(smem, feat, wtp, al, ar, hbf, el, er, N, blockIdx.x - npart);
}

// ---------------- bucket gather: LDS counting sort + softmax + aggregate + epilogue ----------------
__global__ __launch_bounds__(256) void bucket_gather(const unsigned short* __restrict__ hbf,
                                                     const float* __restrict__ el,
                                                     const float* __restrict__ er,
                                                     const int* __restrict__ bcnt,
                                                     const int* __restrict__ tmp,
                                                     const float* __restrict__ feat,
                                                     float* __restrict__ out, int N) {
  __shared__ unsigned short as_s[CAPFIX];       // 1 KB
  __shared__ unsigned short as_a[CAPFIX * 4];   // 4 KB
  __shared__ f32x4 er_l[BN];
  __shared__ int cnt[BN], lb[BN], lc2[BN];
  int t = threadIdx.x;
  int bkt = blockIdx.x;
  int nstart = bkt << BSH;
  if (t < BN) {
    int nd = nstart + t;
    f32x4 e4 = {};
    if (nd < N) e4 = *(const f32x4*)(er + (size_t)nd * 4);
    er_l[t] = e4;
    cnt[t] = 0;
    lc2[t] = 0;
  }
  __syncthreads();
  int nrec = min(bcnt[bkt], CAPFIX);
  int myrec[2], mydlo[2];
#pragma unroll
  for (int i = 0; i < 2; ++i) {
    int idx = t + i * 256;
    mydlo[i] = -1;
    if (idx < nrec) {
      int r = tmp[(size_t)bkt * CAPFIX + idx];
      myrec[i] = r;
      int dlo = (r >> 16) & (BN - 1);
      mydlo[i] = dlo;
      atomicAdd(&cnt[dlo], 1);
    }
  }
  __syncthreads();
  if (t < BN) {
    int v = cnt[t];
    int s = v;
#pragma unroll
    for (int o = 1; o < BN; o <<= 1) {
      int x = __shfl_up(s, o, BN);
      if (t >= o) s += x;
    }
    lb[t] = s - v;
  }
  __syncthreads();
#pragma unroll
  for (int i = 0; i < 2; ++i) {
    if (mydlo[i] >= 0) {
      int r = myrec[i];
      int s = r & 0xFFFF;
      int dlo = mydlo[i];
      int p = lb[dlo] + atomicAdd(&lc2[dlo], 1);
      f32x4 l4 = *(const f32x4*)(el + (size_t)s * 4);
      f32x4 r4 = er_l[dlo];
      float e0 = l4[0] + r4[0];
      float e1 = l4[1] + r4[1];
      float e2 = l4[2] + r4[2];
      float e3 = l4[3] + r4[3];
      e0 = e0 > 0.f ? e0 : 0.01f * e0;
      e1 = e1 > 0.f ? e1 : 0.01f * e1;
      e2 = e2 > 0.f ? e2 : 0.01f * e2;
      e3 = e3 > 0.f ? e3 : 0.01f * e3;
      float m = fmaxf(fmaxf(e0, e1), fmaxf(e2, e3));
      float a0 = __expf(e0 - m);
      float a1 = __expf(e1 - m);
      float a2 = __expf(e2 - m);
      float a3 = __expf(e3 - m);
      float inv = 1.0f / (a0 + a1 + a2 + a3);
      u16x4 a = {f2bf(a0 * inv), f2bf(a1 * inv), f2bf(a2 * inv), f2bf(a3 * inv)};
      as_s[p] = (unsigned short)s;
      *(u16x4*)&as_a[p * 4] = a;
    }
  }
  __syncthreads();
  // one 64-lane wave per node: lane covers h columns [lane*2, lane*2+1]
  int wv = t >> 6;          // wave 0..3
  int lane = t & 63;
  int head = lane >> 4;     // (lane*2)>>5
#pragma unroll
  for (int ni = 0; ni < 4; ++ni) {
    int g = wv * 4 + ni;
    int nd = nstart + g;
    f32x2 acc = {};
    if (nd < N) acc = *(const f32x2*)(feat + (size_t)nd * 128 + lane * 2);
    int st = lb[g], en = st + cnt[g];
    int e = st;
    for (; e + 7 < en; e += 8) {
      f32x2 hx[8];
      float ax[8];
#pragma unroll
      for (int j = 0; j < 8; ++j) {
        int sj = as_s[e + j];
        ax[j] = bf2f(as_a[(e + j) * 4 + head]);
        u16x2 vj = *(const u16x2*)&hbf[(size_t)sj * 128 + lane * 2];
        hx[j] = f32x2{bf2f(vj[0]), bf2f(vj[1])};
      }
#pragma unroll
      for (int j = 0; j < 8; ++j) acc += hx[j] * ax[j];
    }
    for (; e < en; ++e) {
      int s0 = as_s[e];
      float a0 = bf2f(as_a[e * 4 + head]);
      u16x2 v0 = *(const u16x2*)&hbf[(size_t)s0 * 128 + lane * 2];
      acc += f32x2{bf2f(v0[0]), bf2f(v0[1])} * a0;
    }
    if (nd < N) {
      f32x2 o = acc;
      o[0] = o[0] > 0.f ? o[0] : expm1f(o[0]);
      o[1] = o[1] > 0.f ? o[1] : expm1f(o[1]);
      *(f32x2*)(out + (size_t)nd * 128 + lane * 2) = o;
    }
  }
}

extern "C" void kernel_launch(void* const* d_in, const int* in_sizes, int n_in,
                              void* d_out, int out_size, void* d_ws, size_t ws_size,
                              hipStream_t stream) {
  const float* feat = (const float*)d_in[0];
  const int* src = (const int*)d_in[1];
  const int* dst = (const int*)d_in[2];
  const float* W = (const float*)d_in[3];
  const float* al = (const float*)d_in[4];
  const float* ar = (const float*)d_in[5];
  float* out = (float*)d_out;

  int N = in_sizes[0] / 128;
  int E = in_sizes[1];
  int nbuck = (N + BN - 1) >> BSH;

  char* p = (char*)d_ws;
  unsigned short* hbf = (unsigned short*)p; p += (size_t)N * 128 * 2;
  float* el = (float*)p; p += (size_t)N * 4 * 4;
  float* er = (float*)p; p += (size_t)N * 4 * 4;
  unsigned short* wtp = (unsigned short*)p; p += 2048 * 16;
  int* bcursor = (int*)p; p += (size_t)((nbuck + 3) & ~3) * 4;
  int* tmp = (int*)p;  // nbuck * CAPFIX ints

  int npart = (E + PCH - 1) / PCH;
  int nfc = (N + FC_ROWS - 1) / FC_ROWS;

  prezero_kernel<<<8 + (nbuck + 255) / 256, 256, 0, stream>>>(W, wtp, bcursor, nbuck);
  fused_pfc<<<npart + nfc, 256, 0, stream>>>(src, dst, bcursor, tmp, feat, wtp, al, ar,
                                             hbf, el, er, E, N, nbuck, npart);
  bucket_gather<<<nbuck, 256, 0, stream>>>(hbf, el, er, bcursor, tmp, feat, out, N);
}

// Round 11
// 70.444 us; speedup vs baseline: 1.5605x; 1.5605x over previous
//
#include <hip/hip_runtime.h>

typedef float f32x2 __attribute__((ext_vector_type(2)));
typedef float f32x4 __attribute__((ext_vector_type(4)));
typedef __bf16 bf16x8 __attribute__((ext_vector_type(8)));
typedef unsigned short u16x2 __attribute__((ext_vector_type(2)));
typedef unsigned short u16x4 __attribute__((ext_vector_type(4)));
typedef unsigned short u16x8 __attribute__((ext_vector_type(8)));

#define BSH 5            // bucket = 32 dst nodes
#define BN 32
#define CAPFIX 1024      // slots per bucket region (mean 512, +22 sigma)
#define PNB_MAX 1568     // >= nbuck = ceil(50000/32) = 1563
#define SCH 7            // scan entries per thread (256*7 >= PNB_MAX)
#define PCH 4096         // edges per partition block (196 blocks)
#define FC_ROWS 64
// partition smem: cnt,gbase,lpos,sbase [PNB_MAX] + buf[PCH] + ts[256]
#define SMEM_BYTES (4 * PNB_MAX * 4 + PCH * 4 + 256 * 4)

__device__ inline unsigned short f2bf(float x) {
  unsigned int u = __builtin_bit_cast(unsigned int, x);
  unsigned int r = (u + 0x7FFFu + ((u >> 16) & 1u)) >> 16;
  return (unsigned short)r;
}
__device__ inline float bf2f(unsigned short h) {
  unsigned int u = ((unsigned int)h) << 16;
  return __builtin_bit_cast(float, u);
}

// ---------------- prezero: zero bcursor (blocks >= 8) + pack W (blocks 0..7) ----------------
__global__ __launch_bounds__(256) void prezero_kernel(const float* __restrict__ W,
                                                      unsigned short* __restrict__ wtp,
                                                      int* __restrict__ bcursor, int n) {
  int b = blockIdx.x;
  if (b < 8) {
    int tid = b * 256 + threadIdx.x;  // 2048 chunks
    int col = tid & 127;
    int kg = tid >> 7;
    float v[8];
#pragma unroll
    for (int j = 0; j < 8; ++j) v[j] = W[(kg * 8 + j) * 128 + col];
    u16x8 pk = {f2bf(v[0]), f2bf(v[1]), f2bf(v[2]), f2bf(v[3]),
                f2bf(v[4]), f2bf(v[5]), f2bf(v[6]), f2bf(v[7])};
    *(u16x8*)&wtp[(size_t)(kg * 128 + col) * 8] = pk;
  } else {
    int i = (b - 8) * 256 + threadIdx.x;
    if (i < n) bcursor[i] = 0;
  }
}

// ---------------- partition body: LDS counting sort + coalesced copy-out ----------------
__device__ void partition_body(char* smem, const int* __restrict__ src,
                               const int* __restrict__ dst,
                               int* __restrict__ bcursor, int* __restrict__ tmp,
                               int E, int nbuck, int blk) {
  int* cnt = (int*)smem;
  int* gbase = cnt + PNB_MAX;
  int* lpos = gbase + PNB_MAX;
  int* sbase = lpos + PNB_MAX;
  int* buf = sbase + PNB_MAX;
  int* ts = buf + PCH;
  int t = threadIdx.x;
  int base = blk * PCH;
  int nedge = E - base;
  if (nedge > PCH) nedge = PCH;
  for (int i = t; i < nbuck; i += 256) cnt[i] = 0;
  __syncthreads();
  // phase A: histogram + register-cache records
  int rec[16], bb[16];
#pragma unroll
  for (int i = 0; i < 16; ++i) {
    int e = base + t + i * 256;
    bb[i] = -1;
    if (e < E) {
      int d = dst[e];
      int b = d >> BSH;
      bb[i] = b;
      rec[i] = (src[e] & 0xFFFF) | ((d & (BN - 1)) << 16) | (b << 21);
      atomicAdd(&cnt[b], 1);
    }
  }
  __syncthreads();
  // phase B1: reserve global ranges
  for (int i = t; i < nbuck; i += 256) {
    int c = cnt[i];
    gbase[i] = c ? atomicAdd(&bcursor[i], c) : 0;
  }
  // phase B2: block-exclusive scan of cnt -> sbase/lpos
  {
    int t0 = t * SCH;
    int loc[SCH];
    int s = 0;
#pragma unroll
    for (int j = 0; j < SCH; ++j) {
      int idx = t0 + j;
      loc[j] = s;
      s += (idx < nbuck) ? cnt[idx] : 0;
    }
    ts[t] = s;
    __syncthreads();
    for (int o = 1; o < 256; o <<= 1) {
      int x = (t >= o) ? ts[t - o] : 0;
      __syncthreads();
      ts[t] += x;
      __syncthreads();
    }
    int pre = ts[t] - s;
#pragma unroll
    for (int j = 0; j < SCH; ++j) {
      int idx = t0 + j;
      if (idx < nbuck) {
        int v = pre + loc[j];
        sbase[idx] = v;
        lpos[idx] = v;
      }
    }
  }
  __syncthreads();
  // phase C: scatter records into sorted LDS buffer
#pragma unroll
  for (int i = 0; i < 16; ++i) {
    if (bb[i] >= 0) {
      int p = atomicAdd(&lpos[bb[i]], 1);
      buf[p] = rec[i];
    }
  }
  __syncthreads();
  // phase D: coalesced copy-out (consecutive slots -> consecutive tmp addrs per run)
#pragma unroll
  for (int i = 0; i < 16; ++i) {
    int idx = t + i * 256;
    if (idx < nedge) {
      int r = buf[idx];
      int b = (unsigned)r >> 21;
      int off = gbase[b] + (idx - sbase[b]);
      if (off < CAPFIX) tmp[(size_t)b * CAPFIX + off] = r;
    }
  }
}

// ---------------- fc body: h = feat @ W via MFMA; B-fragments from L1-resident wtp ----------------
__device__ void fc_body(char* smem, const float* __restrict__ feat,
                        const unsigned short* __restrict__ wtp,
                        const float* __restrict__ al, const float* __restrict__ ar,
                        unsigned short* __restrict__ hbf,
                        float* __restrict__ el, float* __restrict__ er,
                        int N, int blk) {
  unsigned short* Albs = (unsigned short*)smem;  // 16 KB
  int t = threadIdx.x;
  int row0 = blk * FC_ROWS;
#pragma unroll
  for (int i = 0; i < 4; ++i) {
    int ch = i * 256 + t;
    int row = ch >> 4;
    int kg = ch & 15;
    int grow = row0 + row;
    f32x4 x0 = {}, x1 = {};
    if (grow < N) {
      const f32x4* fp = (const f32x4*)(feat + (size_t)grow * 128 + kg * 8);
      x0 = fp[0];
      x1 = fp[1];
    }
    int sc = kg * 64 + (row ^ kg);
    u16x8 pk = {f2bf(x0[0]), f2bf(x0[1]), f2bf(x0[2]), f2bf(x0[3]),
                f2bf(x1[0]), f2bf(x1[1]), f2bf(x1[2]), f2bf(x1[3])};
    *(u16x8*)&Albs[sc * 8] = pk;
  }
  __syncthreads();
  int w = t >> 6;
  int l = t & 63;
  int lr = l & 15;
  int lhi = l >> 4;
  f32x4 acc[8] = {};
  bf16x8 afr[4];
#pragma unroll
  for (int ks = 0; ks < 4; ++ks) {
    int kg = ks * 4 + lhi;
    int row = w * 16 + lr;
    afr[ks] = *(const bf16x8*)&Albs[(kg * 64 + (row ^ kg)) * 8];
  }
#pragma unroll
  for (int nt = 0; nt < 8; ++nt) {
#pragma unroll
    for (int ks = 0; ks < 4; ++ks) {
      int kg = ks * 4 + lhi;
      int col = nt * 16 + lr;
      bf16x8 b = *(const bf16x8*)&wtp[(size_t)(kg * 128 + col) * 8];
      acc[nt] = __builtin_amdgcn_mfma_f32_16x16x32_bf16(afr[ks], b, acc[nt], 0, 0, 0);
    }
  }
#pragma unroll
  for (int nt = 0; nt < 8; ++nt) {
#pragma unroll
    for (int r = 0; r < 4; ++r) {
      int g = row0 + w * 16 + lhi * 4 + r;
      if (g < N) hbf[(size_t)g * 128 + nt * 16 + lr] = f2bf(acc[nt][r]);
    }
  }
  f32x4 pl[4] = {}, pr[4] = {};
#pragma unroll
  for (int nt = 0; nt < 8; ++nt) {
    int hd = nt >> 1;
    float wl = al[nt * 16 + lr];
    float wr = ar[nt * 16 + lr];
#pragma unroll
    for (int r = 0; r < 4; ++r) {
      pl[r][hd] += acc[nt][r] * wl;
      pr[r][hd] += acc[nt][r] * wr;
    }
  }
#pragma unroll
  for (int off = 1; off < 16; off <<= 1) {
#pragma unroll
    for (int r = 0; r < 4; ++r) {
#pragma unroll
      for (int c = 0; c < 4; ++c) {
        pl[r][c] += __shfl_xor(pl[r][c], off);
        pr[r][c] += __shfl_xor(pr[r][c], off);
      }
    }
  }
  if (lr == 0) {
#pragma unroll
    for (int r = 0; r < 4; ++r) {
      int g = row0 + w * 16 + lhi * 4 + r;
      if (g < N) *(f32x4*)(el + (size_t)g * 4) = pl[r];
    }
  } else if (lr == 1) {
#pragma unroll
    for (int r = 0; r < 4; ++r) {
      int g = row0 + w * 16 + lhi * 4 + r;
      if (g < N) *(f32x4*)(er + (size_t)g * 4) = pr[r];
    }
  }
}

// ---------------- fused: partition blocks + fc blocks in one grid ----------------
__global__ __launch_bounds__(256) void fused_pfc(const int* __restrict__ src,
                                                 const int* __restrict__ dst,
                                                 int* __restrict__ bcursor,
                                                 int* __restrict__ tmp,
                                                 const float* __restrict__ feat,
                                                 const unsigned short* __restrict__ wtp,
                                                 const float* __restrict__ al,
                                                 const float* __restrict__ ar,
                                                 unsigned short* __restrict__ hbf,
                                                 float* __restrict__ el,
                                                 float* __restrict__ er,
                                                 int E, int N, int nbuck, int npart) {
  __shared__ alignas(16) char smem[SMEM_BYTES];
  if ((int)blockIdx.x < npart)
    partition_body(smem, src, dst, bcursor, tmp, E, nbuck, blockIdx.x);
  else
    fc_body(smem, feat, wtp, al, ar, hbf, el, er, N, blockIdx.x - npart);
}

// ---------------- bucket gather: LDS counting sort + softmax + aggregate + epilogue ----------------
__global__ __launch_bounds__(256) void bucket_gather(const unsigned short* __restrict__ hbf,
                                                     const float* __restrict__ el,
                                                     const float* __restrict__ er,
                                                     const int* __restrict__ bcnt,
                                                     const int* __restrict__ tmp,
                                                     const float* __restrict__ feat,
                                                     float* __restrict__ out, int N) {
  __shared__ unsigned short as_s[CAPFIX];       // 2 KB
  __shared__ unsigned short as_a[CAPFIX * 4];   // 8 KB
  __shared__ f32x4 er_l[BN];
  __shared__ int cnt[BN], lb[BN], lc2[BN];
  int t = threadIdx.x;
  int bkt = blockIdx.x;
  int nstart = bkt << BSH;
  if (t < BN) {
    int nd = nstart + t;
    f32x4 e4 = {};
    if (nd < N) e4 = *(const f32x4*)(er + (size_t)nd * 4);
    er_l[t] = e4;
    cnt[t] = 0;
    lc2[t] = 0;
  }
  __syncthreads();
  int nrec = min(bcnt[bkt], CAPFIX);
  int myrec[4], mydlo[4];
#pragma unroll
  for (int i = 0; i < 4; ++i) {
    int idx = t + i * 256;
    mydlo[i] = -1;
    if (idx < nrec) {
      int r = tmp[(size_t)bkt * CAPFIX + idx];
      myrec[i] = r;
      int dlo = (r >> 16) & (BN - 1);
      mydlo[i] = dlo;
      atomicAdd(&cnt[dlo], 1);
    }
  }
  __syncthreads();
  if (t < BN) {
    int v = cnt[t];
    int s = v;
#pragma unroll
    for (int o = 1; o < BN; o <<= 1) {
      int x = __shfl_up(s, o, BN);
      if (t >= o) s += x;
    }
    lb[t] = s - v;
  }
  __syncthreads();
#pragma unroll
  for (int i = 0; i < 4; ++i) {
    if (mydlo[i] >= 0) {
      int r = myrec[i];
      int s = r & 0xFFFF;
      int dlo = mydlo[i];
      int p = lb[dlo] + atomicAdd(&lc2[dlo], 1);
      f32x4 l4 = *(const f32x4*)(el + (size_t)s * 4);
      f32x4 r4 = er_l[dlo];
      float e0 = l4[0] + r4[0];
      float e1 = l4[1] + r4[1];
      float e2 = l4[2] + r4[2];
      float e3 = l4[3] + r4[3];
      e0 = e0 > 0.f ? e0 : 0.01f * e0;
      e1 = e1 > 0.f ? e1 : 0.01f * e1;
      e2 = e2 > 0.f ? e2 : 0.01f * e2;
      e3 = e3 > 0.f ? e3 : 0.01f * e3;
      float m = fmaxf(fmaxf(e0, e1), fmaxf(e2, e3));
      float a0 = __expf(e0 - m);
      float a1 = __expf(e1 - m);
      float a2 = __expf(e2 - m);
      float a3 = __expf(e3 - m);
      float inv = 1.0f / (a0 + a1 + a2 + a3);
      u16x4 a = {f2bf(a0 * inv), f2bf(a1 * inv), f2bf(a2 * inv), f2bf(a3 * inv)};
      as_s[p] = (unsigned short)s;
      *(u16x4*)&as_a[p * 4] = a;
    }
  }
  __syncthreads();
  // one 64-lane wave per node: lane covers h columns [lane*2, lane*2+1]
  int wv = t >> 6;          // wave 0..3
  int lane = t & 63;
  int head = lane >> 4;     // (lane*2)>>5
#pragma unroll
  for (int ni = 0; ni < 8; ++ni) {
    int g = wv * 8 + ni;
    int nd = nstart + g;
    f32x2 acc = {};
    if (nd < N) acc = *(const f32x2*)(feat + (size_t)nd * 128 + lane * 2);
    int st = lb[g], en = st + cnt[g];
    int e = st;
    for (; e + 7 < en; e += 8) {
      f32x2 hx[8];
      float ax[8];
#pragma unroll
      for (int j = 0; j < 8; ++j) {
        int sj = as_s[e + j];
        ax[j] = bf2f(as_a[(e + j) * 4 + head]);
        u16x2 vj = *(const u16x2*)&hbf[(size_t)sj * 128 + lane * 2];
        hx[j] = f32x2{bf2f(vj[0]), bf2f(vj[1])};
      }
#pragma unroll
      for (int j = 0; j < 8; ++j) acc += hx[j] * ax[j];
    }
    for (; e < en; ++e) {
      int s0 = as_s[e];
      float a0 = bf2f(as_a[e * 4 + head]);
      u16x2 v0 = *(const u16x2*)&hbf[(size_t)s0 * 128 + lane * 2];
      acc += f32x2{bf2f(v0[0]), bf2f(v0[1])} * a0;
    }
    if (nd < N) {
      f32x2 o = acc;
      o[0] = o[0] > 0.f ? o[0] : expm1f(o[0]);
      o[1] = o[1] > 0.f ? o[1] : expm1f(o[1]);
      *(f32x2*)(out + (size_t)nd * 128 + lane * 2) = o;
    }
  }
}

extern "C" void kernel_launch(void* const* d_in, const int* in_sizes, int n_in,
                              void* d_out, int out_size, void* d_ws, size_t ws_size,
                              hipStream_t stream) {
  const float* feat = (const float*)d_in[0];
  const int* src = (const int*)d_in[1];
  const int* dst = (const int*)d_in[2];
  const float* W = (const float*)d_in[3];
  const float* al = (const float*)d_in[4];
  const float* ar = (const float*)d_in[5];
  float* out = (float*)d_out;

  int N = in_sizes[0] / 128;
  int E = in_sizes[1];
  int nbuck = (N + BN - 1) >> BSH;

  char* p = (char*)d_ws;
  unsigned short* hbf = (unsigned short*)p; p += (size_t)N * 128 * 2;
  float* el = (float*)p; p += (size_t)N * 4 * 4;
  float* er = (float*)p; p += (size_t)N * 4 * 4;
  unsigned short* wtp = (unsigned short*)p; p += 2048 * 16;
  int* bcursor = (int*)p; p += (size_t)((nbuck + 3) & ~3) * 4;
  int* tmp = (int*)p;  // nbuck * CAPFIX ints

  int npart = (E + PCH - 1) / PCH;
  int nfc = (N + FC_ROWS - 1) / FC_ROWS;

  prezero_kernel<<<8 + (nbuck + 255) / 256, 256, 0, stream>>>(W, wtp, bcursor, nbuck);
  fused_pfc<<<npart + nfc, 256, 0, stream>>>(src, dst, bcursor, tmp, feat, wtp, al, ar,
                                             hbf, el, er, E, N, nbuck, npart);
  bucket_gather<<<nbuck, 256, 0, stream>>>(hbf, el, er, bcursor, tmp, feat, out, N);
}